// Round 1
// baseline (258.230 us; speedup 1.0000x reference)
//
#include <hip/hip_runtime.h>
#include <math.h>

#define NBb 16
#define NTt 50
#define NAa 5
#define NHh 128
#define NWw 128
#define NCc 20
#define NCH 26                       // 6 + NC channels
#define NCELL (NBb*NAa*NHh*NWw)      // 1,310,720 cells
#define NREC  (NBb*NTt)              // 800 records
#define SCALE_F 16.0f
#define IGNORE_THRES_F 0.5f
#define BAD_CONF_WEIGHT_F 1.25f
#define PI_F 3.14159265358979323846f

// ws layout (float units):
//  [0..15]   accumulators: 0 acc_bg, 1 cnt_bg, 2 acc_obj, 3 acc_x, 4 acc_y,
//            5 acc_w, 6 acc_h, 7 acc_r, 8 acc_cls, 9 cnt_mask
//  [16 .. 16+NCELL)            status grid (uint32): 0=bg, 1=ignored, 2+rec=masked
//  [16+NCELL .. 16+NCELL+4800) records: tx,ty,tw,th,tr (float[800] each), tlab (int[800])
#define STATUS_OFF_F 16
#define REC_OFF_F (16 + NCELL)

__device__ __forceinline__ float inv_tanh_f(float y) {
  if (y <= -1.0f) return -2.0f;
  if (y >= 1.0f)  return  2.0f;
  float ys = fminf(fmaxf(y, -1.0f + 1e-6f), 1.0f - 1e-6f);
  return 0.5f * logf((1.0f + ys) / (1.0f - ys));
}

// softplus(z) = max(z,0) + log1p(exp(-|z|))  == BCE(z, target=0)
__device__ __forceinline__ float softplus_f(float z) {
  return fmaxf(z, 0.0f) + log1pf(expf(-fabsf(z)));
}

__global__ void k_prep(const float* __restrict__ tgt,
                       const int* __restrict__ tsz,
                       const float* __restrict__ anch,
                       float* __restrict__ ws) {
  int tid = blockIdx.x * blockDim.x + threadIdx.x;
  if (tid >= NREC) return;
  int b = tid / NTt, t = tid % NTt;

  // per-anchor constants (5 anchors, cheap to recompute per thread)
  float aw[NAa], ah[NAa], ar[NAa], ahw[NAa], ap[NAa][8];
  for (int a = 0; a < NAa; ++a) {
    aw[a] = anch[a*3+0] / SCALE_F;
    ah[a] = anch[a*3+1] / SCALE_F;
    ar[a] = anch[a*3+2];
    float cr = cosf(ar[a]), sr = sinf(ar[a]);
    ap[a][0] = -cr*aw[a]; ap[a][1] =  sr*aw[a];
    ap[a][2] =  cr*aw[a]; ap[a][3] = -sr*aw[a];
    ap[a][4] = -sr*ah[a]; ap[a][5] = -cr*ah[a];
    ap[a][6] =  sr*ah[a]; ap[a][7] =  cr*ah[a];
    ahw[a] = (ah[a] + aw[a]) * 0.5f;
  }

  const float* row = tgt + (size_t)tid * (13 + NCc);
  float gx = row[0] / SCALE_F;
  float gy = row[1] / SCALE_F;
  float gr = row[2];
  float gh = row[3] / SCALE_F;
  float gw = row[4] / SCALE_F;
  bool valid = (t < tsz[b]) && (gw != 0.0f) && (gh != 0.0f);
  if (!valid) return;   // invalid rows contribute to no scatter and no record

  int gi = (int)gx; gi = min(max(gi, 0), NWw - 1);   // trunc-toward-zero like astype(int32)
  int gj = (int)gy; gj = min(max(gj, 0), NHh - 1);

  float cp[8];
  for (int k = 0; k < 8; ++k)
    cp[k] = row[5 + k] / SCALE_F - ((k & 1) ? gy : gx);

  float bestd = 1e30f; int best = 0; unsigned ignm = 0;
  for (int a = 0; a < NAa; ++a) {
    float dn = 0.0f;
    for (int p = 0; p < 8; p += 2) {
      float dx = cp[p]   - ap[a][p];
      float dy = cp[p+1] - ap[a][p+1];
      dn += sqrtf(dx*dx + dy*dy);
    }
    float nm = ((gh + gw) * 0.5f + ahw[a]) * 0.5f;
    float d = dn / nm; d = d * d;
    if (d < IGNORE_THRES_F) ignm |= (1u << a);
    if (d < bestd) { bestd = d; best = a; }   // strict < -> first-occurrence argmin
  }

  unsigned* status = (unsigned*)(ws + STATUS_OFF_F);
  int cellbase = ((b * NAa) * NHh + gj) * NWw + gi;
  // ignore scatter: value 1 (never overrides a mask write, which is >= 2)
  for (int a = 0; a < NAa; ++a)
    if ((ignm >> a) & 1u) atomicMax(&status[cellbase + a * NHh * NWw], 1u);
  // mask scatter: 2+rec; atomicMax => mask beats ignore, largest t (last write) wins
  atomicMax(&status[cellbase + best * NHh * NWw], 2u + (unsigned)tid);

  // record fields
  float txv = inv_tanh_f(gx - ((float)gi + 0.5f));
  float tyv = inv_tanh_f(gy - ((float)gj + 0.5f));
  float rd = gr - ar[best];
  if (rd > PI_F) rd -= 2.0f * PI_F;
  else if (rd < -PI_F) rd += 2.0f * PI_F;
  float trv = inv_tanh_f(rd / (PI_F * 0.5f));
  float twv = logf(gw / aw[best] + 1e-16f);
  float thv = logf(gh / ah[best] + 1e-16f);
  int tlab = 0; float bm = row[13];
  for (int c = 1; c < NCc; ++c)
    if (row[13 + c] > bm) { bm = row[13 + c]; tlab = c; }

  float* rec = ws + REC_OFF_F;
  rec[0*NREC + tid] = txv;
  rec[1*NREC + tid] = tyv;
  rec[2*NREC + tid] = twv;
  rec[3*NREC + tid] = thv;
  rec[4*NREC + tid] = trv;
  ((int*)rec)[5*NREC + tid] = tlab;
}

__global__ void k_main(const float* __restrict__ pred, float* __restrict__ ws) {
  const unsigned* __restrict__ status = (const unsigned*)(ws + STATUS_OFF_F);
  const float* __restrict__ rec = ws + REC_OFF_F;
  float acc_bg = 0.0f, cnt_bg = 0.0f;
  int stride = gridDim.x * blockDim.x;
  for (int i = blockIdx.x * blockDim.x + threadIdx.x; i < NCELL; i += stride) {
    unsigned st = status[i];
    const float* cell = pred + (size_t)i * NCH;
    if (st == 0u) {
      acc_bg += softplus_f(cell[0]);
      cnt_bg += 1.0f;
    } else if (st >= 2u) {
      // rare path: <= 800 of 1.31M cells
      int r = (int)(st - 2u);
      float z = cell[0];
      float lobj = softplus_f(z) - z;                 // BCE(z, target=1)
      float dx = cell[1] - rec[0*NREC + r];
      float dy = cell[2] - rec[1*NREC + r];
      float dr = cell[3] - rec[4*NREC + r];
      float dh = cell[4] - rec[3*NREC + r];
      float dw = cell[5] - rec[2*NREC + r];
      int tlab = ((const int*)rec)[5*NREC + r];
      float m = cell[6];
      for (int c = 1; c < NCc; ++c) m = fmaxf(m, cell[6 + c]);
      float s = 0.0f;
      for (int c = 0; c < NCc; ++c) s += expf(cell[6 + c] - m);
      float nll = (m + logf(s)) - cell[6 + tlab];
      atomicAdd(ws + 2, lobj);
      atomicAdd(ws + 3, dx * dx);
      atomicAdd(ws + 4, dy * dy);
      atomicAdd(ws + 5, dw * dw);
      atomicAdd(ws + 6, dh * dh);
      atomicAdd(ws + 7, dr * dr);
      atomicAdd(ws + 8, nll);
      atomicAdd(ws + 9, 1.0f);
    }
    // st == 1 (ignored, not masked): contributes nothing anywhere
  }
  // block reduce acc_bg / cnt_bg -> one atomic pair per block
  for (int off = 32; off; off >>= 1) {
    acc_bg += __shfl_down(acc_bg, off, 64);
    cnt_bg += __shfl_down(cnt_bg, off, 64);
  }
  __shared__ float s0[8], s1[8];
  int wid = threadIdx.x >> 6, lane = threadIdx.x & 63;
  if (lane == 0) { s0[wid] = acc_bg; s1[wid] = cnt_bg; }
  __syncthreads();
  if (threadIdx.x == 0) {
    float a = 0.0f, c = 0.0f;
    int nw = blockDim.x >> 6;
    for (int w = 0; w < nw; ++w) { a += s0[w]; c += s1[w]; }
    atomicAdd(ws + 0, a);
    atomicAdd(ws + 1, c);
  }
}

__global__ void k_final(const float* __restrict__ ws, float* __restrict__ out) {
  float acc_bg = ws[0], cnt_bg = ws[1], acc_obj = ws[2];
  float ax = ws[3], ay = ws[4], aww = ws[5], ahh = ws[6], arr = ws[7], acls = ws[8];
  float cm = ws[9];
  float db = fmaxf(cnt_bg, 1.0f);
  float dm = fmaxf(cm, 1.0f);
  float loss_conf = BAD_CONF_WEIGHT_F * (acc_bg / db) + acc_obj / dm;
  out[0] = (ax + ay + aww + ahh + arr + acls) / dm + loss_conf;
}

extern "C" void kernel_launch(void* const* d_in, const int* in_sizes, int n_in,
                              void* d_out, int out_size, void* d_ws, size_t ws_size,
                              hipStream_t stream) {
  const float* pred = (const float*)d_in[0];   // (16,5,128,128,26)
  const float* tgt  = (const float*)d_in[1];   // (16,50,33)
  const int*   tsz  = (const int*)d_in[2];     // (16,)
  const float* anch = (const float*)d_in[3];   // (5,3)
  float* ws = (float*)d_ws;

  // zero accumulators + status grid (records don't need init)
  hipMemsetAsync(d_ws, 0, (size_t)(STATUS_OFF_F + NCELL) * sizeof(float), stream);
  k_prep<<<4, 256, 0, stream>>>(tgt, tsz, anch, ws);
  k_main<<<1280, 256, 0, stream>>>(pred, ws);
  k_final<<<1, 1, 0, stream>>>(ws, (float*)d_out);
}